// Round 3
// baseline (433.957 us; speedup 1.0000x reference)
//
#include <hip/hip_runtime.h>
#include <hip/hip_bf16.h>

#define NN 50000
#define EE 800000
#define CIN 256
#define HEADS 4
#define HDIM 32

typedef float f32x4 __attribute__((ext_vector_type(4)));
typedef __bf16 bf16x8 __attribute__((ext_vector_type(8)));

typedef const __attribute__((address_space(1))) unsigned int* gptr_t;
typedef __attribute__((address_space(3))) unsigned int* lptr_t;

static __device__ __forceinline__ unsigned short f2b(float f) {
    __hip_bfloat16 h = __float2bfloat16(f);
    return *(unsigned short*)&h;
}
static __device__ __forceinline__ float blo(unsigned int u) {
    union { unsigned int i; float f; } c; c.i = u << 16; return c.f;
}
static __device__ __forceinline__ float bhi(unsigned int u) {
    union { unsigned int i; float f; } c; c.i = u & 0xffff0000u; return c.f;
}

// ---------------- prep: x -> bf16 ----------------
__global__ __launch_bounds__(256) void prep_x(const float* __restrict__ x,
                                              unsigned short* __restrict__ xb) {
    const int t = blockIdx.x * 256 + threadIdx.x;     // one thread per 8 elements
    if (t >= NN * CIN / 8) return;
    const float4 a = ((const float4*)x)[t * 2];
    const float4 b = ((const float4*)x)[t * 2 + 1];
    union { unsigned short us[8]; uint4 v; } o;
    o.us[0] = f2b(a.x); o.us[1] = f2b(a.y); o.us[2] = f2b(a.z); o.us[3] = f2b(a.w);
    o.us[4] = f2b(b.x); o.us[5] = f2b(b.y); o.us[6] = f2b(b.z); o.us[7] = f2b(b.w);
    ((uint4*)xb)[t] = o.v;
}

// ---------------- prep: WT[416][256] bf16 (transposed concat) ----------------
__global__ __launch_bounds__(256) void prep_w(
    const float* __restrict__ Wq, const float* __restrict__ Wk,
    const float* __restrict__ Wv, const float* __restrict__ Ws,
    unsigned short* __restrict__ WT) {
    const int t = blockIdx.x * 256 + threadIdx.x;     // c*256 + k
    if (t >= 416 * 256) return;
    const int c = t >> 8;
    const int k = t & 255;
    float w;
    if (c < 128)      w = Wq[k * 128 + c];
    else if (c < 256) w = Wk[k * 128 + (c - 128)];
    else if (c < 384) w = Wv[k * 128 + (c - 256)];
    else              w = Ws[k * 32 + (c - 384)];
    WT[t] = f2b(w);
}

// ---------------- MFMA GEMM: [N][256]bf16 @ WT -> q/k/v bf16, skip f32 ------
__global__ __launch_bounds__(256) void mfma_gemm(
    const unsigned short* __restrict__ xb, const unsigned short* __restrict__ WT,
    const float* __restrict__ bq, const float* __restrict__ bk,
    const float* __restrict__ bv, const float* __restrict__ bs,
    unsigned short* __restrict__ qb, unsigned short* __restrict__ kb,
    unsigned short* __restrict__ vb, float* __restrict__ skip) {
    __shared__ __hip_bfloat16 As[128 * 32];
    __shared__ __hip_bfloat16 Bs[32 * 32];

    const int row0 = blockIdx.x * 128;
    const int col0 = blockIdx.y * 32;
    const int wave = threadIdx.x >> 6;
    const int lane = threadIdx.x & 63;
    const int lr = lane & 15;
    const int lq = lane >> 4;

    f32x4 acc[2][2] = {};

    for (int k0 = 0; k0 < CIN; k0 += 32) {
        #pragma unroll
        for (int i = 0; i < 2; ++i) {
            const int u = wave * 128 + i * 64 + lane;
            const int r = u >> 2, cb = u & 3;
            int grow = row0 + r; if (grow >= NN) grow = NN - 1;
            __builtin_amdgcn_global_load_lds(
                (gptr_t)(const void*)(xb + (size_t)grow * CIN + k0 + cb * 8),
                (lptr_t)(void*)((__hip_bfloat16*)As + u * 8), 16, 0, 0);
        }
        if (wave < 2) {
            const int u = wave * 64 + lane;
            const int c = u >> 2, cb = u & 3;
            __builtin_amdgcn_global_load_lds(
                (gptr_t)(const void*)(WT + (size_t)(col0 + c) * CIN + k0 + cb * 8),
                (lptr_t)(void*)((__hip_bfloat16*)Bs + u * 8), 16, 0, 0);
        }
        __syncthreads();

        bf16x8 af[2], bfr[2];
        af[0]  = *(const bf16x8*)(As + (wave * 32 +  0 + lr) * 32 + lq * 8);
        af[1]  = *(const bf16x8*)(As + (wave * 32 + 16 + lr) * 32 + lq * 8);
        bfr[0] = *(const bf16x8*)(Bs + ( 0 + lr) * 32 + lq * 8);
        bfr[1] = *(const bf16x8*)(Bs + (16 + lr) * 32 + lq * 8);

        acc[0][0] = __builtin_amdgcn_mfma_f32_16x16x32_bf16(af[0], bfr[0], acc[0][0], 0, 0, 0);
        acc[0][1] = __builtin_amdgcn_mfma_f32_16x16x32_bf16(af[0], bfr[1], acc[0][1], 0, 0, 0);
        acc[1][0] = __builtin_amdgcn_mfma_f32_16x16x32_bf16(af[1], bfr[0], acc[1][0], 0, 0, 0);
        acc[1][1] = __builtin_amdgcn_mfma_f32_16x16x32_bf16(af[1], bfr[1], acc[1][1], 0, 0, 0);
        __syncthreads();
    }

    #pragma unroll
    for (int i = 0; i < 2; ++i)
        #pragma unroll
        for (int j = 0; j < 2; ++j)
            #pragma unroll
            for (int r = 0; r < 4; ++r) {
                const int grow = row0 + wave * 32 + i * 16 + lq * 4 + r;
                if (grow >= NN) continue;
                const int gcol = col0 + j * 16 + lr;
                const float val = acc[i][j][r];
                if (gcol < 128)
                    qb[(size_t)grow * 128 + gcol] = f2b(val + bq[gcol]);
                else if (gcol < 256)
                    kb[(size_t)grow * 128 + gcol - 128] = f2b(val + bk[gcol - 128]);
                else if (gcol < 384)
                    vb[(size_t)grow * 128 + gcol - 256] = f2b(val + bv[gcol - 256]);
                else
                    skip[(size_t)grow * 32 + gcol - 384] = val + bs[gcol - 384];
            }
}

// ---------------- CSR build ----------------
__global__ __launch_bounds__(256) void hist_dst(const int* __restrict__ ei,
                                                int* __restrict__ deg) {
    const int t = blockIdx.x * 256 + threadIdx.x;
    if (t >= EE) return;
    atomicAdd(&deg[ei[EE + t]], 1);
}

// single-block exclusive scan: row_ptr[i] = sum(deg[0..i-1]), row_ptr[NN] = EE
__global__ __launch_bounds__(1024) void scan_deg(const int* __restrict__ deg,
                                                 int* __restrict__ row_ptr) {
    __shared__ int part[1024];
    const int tid = threadIdx.x;
    const int CH = (NN + 1023) / 1024;       // 49
    const int base = tid * CH;
    int s = 0;
    for (int j = 0; j < CH; ++j) {
        const int idx = base + j;
        if (idx < NN) s += deg[idx];
    }
    part[tid] = s;
    __syncthreads();
    for (int off = 1; off < 1024; off <<= 1) {
        int v = (tid >= off) ? part[tid - off] : 0;
        __syncthreads();
        part[tid] += v;
        __syncthreads();
    }
    int run = (tid > 0) ? part[tid - 1] : 0;
    for (int j = 0; j < CH; ++j) {
        const int idx = base + j;
        if (idx <= NN) row_ptr[idx] = run;
        if (idx < NN) run += deg[idx];
    }
}

__global__ __launch_bounds__(256) void fill_csr(const int* __restrict__ ei,
                                                const int* __restrict__ row_ptr,
                                                int* __restrict__ cursor,
                                                int* __restrict__ csr_src) {
    const int t = blockIdx.x * 256 + threadIdx.x;
    if (t >= EE) return;
    const int dst = ei[EE + t];
    const int pos = atomicAdd(&cursor[dst], 1);
    csr_src[row_ptr[dst] + pos] = ei[t];
}

// ---------------- fused edge pass: one wave per dst node ----------------
// lane = h*16 + i; lane covers head h, dims {2i, 2i+1}
__global__ __launch_bounds__(256) void fused_edge(
    const unsigned short* __restrict__ qb, const unsigned short* __restrict__ kb,
    const unsigned short* __restrict__ vb, const int* __restrict__ csr_src,
    const int* __restrict__ row_ptr, const float* __restrict__ skip,
    float* __restrict__ out) {
    const int wid = blockIdx.x * 4 + (threadIdx.x >> 6);   // node id
    if (wid >= NN) return;
    const int lane = threadIdx.x & 63;
    const int h = lane >> 4;
    const int i = lane & 15;
    const int co = h * 32 + 2 * i;                          // offset into 128-wide row

    const unsigned int qu = *(const unsigned int*)(qb + (size_t)wid * 128 + co);
    const float q0 = blo(qu), q1 = bhi(qu);

    const int beg = row_ptr[wid];
    const int end = row_ptr[wid + 1];

    float s = 0.f, a0 = 0.f, a1 = 0.f;
    int src_next = (beg < end) ? csr_src[beg] : 0;
    for (int p = beg; p < end; ++p) {
        const int src = src_next;
        if (p + 1 < end) src_next = csr_src[p + 1];
        const unsigned int ku = *(const unsigned int*)(kb + (size_t)src * 128 + co);
        const unsigned int vu = *(const unsigned int*)(vb + (size_t)src * 128 + co);
        float d = q0 * blo(ku) + q1 * bhi(ku);
        d += __shfl_xor(d, 1);
        d += __shfl_xor(d, 2);
        d += __shfl_xor(d, 4);
        d += __shfl_xor(d, 8);
        const float w = __expf(d * 0.17677669529663687f);   // 1/sqrt(32)
        s += w;
        a0 += w * blo(vu);
        a1 += w * bhi(vu);
    }
    const float inv = (s > 0.f) ? 1.f / s : 0.f;
    a0 *= inv; a1 *= inv;
    // sum over heads (lanes stride 16 apart hold the 4 head partials of dim pair i)
    a0 += __shfl_xor(a0, 16); a0 += __shfl_xor(a0, 32);
    a1 += __shfl_xor(a1, 16); a1 += __shfl_xor(a1, 32);
    if (h == 0) {
        const float2 sk = *(const float2*)(skip + (size_t)wid * 32 + 2 * i);
        float o0 = 0.25f * a0 + sk.x;
        float o1 = 0.25f * a1 + sk.y;
        o0 = o0 > 0.f ? o0 : 0.1f * o0;
        o1 = o1 > 0.f ? o1 : 0.1f * o1;
        *(float2*)(out + (size_t)wid * 32 + 2 * i) = make_float2(o0, o1);
    }
}

extern "C" void kernel_launch(void* const* d_in, const int* in_sizes, int n_in,
                              void* d_out, int out_size, void* d_ws, size_t ws_size,
                              hipStream_t stream) {
    const float* x  = (const float*)d_in[0];
    const int*   ei = (const int*)d_in[1];
    const float* Wq = (const float*)d_in[2];
    const float* bq = (const float*)d_in[3];
    const float* Wk = (const float*)d_in[4];
    const float* bk = (const float*)d_in[5];
    const float* Wv = (const float*)d_in[6];
    const float* bv = (const float*)d_in[7];
    const float* Ws = (const float*)d_in[8];
    const float* bs = (const float*)d_in[9];
    float* out = (float*)d_out;

    char* ws = (char*)d_ws;
    size_t off = 0;
    auto alloc = [&](size_t bytes) { void* p = ws + off; off = (off + bytes + 255) & ~(size_t)255; return p; };
    unsigned short* xb   = (unsigned short*)alloc((size_t)NN * CIN * 2);   // 25.6 MB
    unsigned short* WT   = (unsigned short*)alloc((size_t)416 * CIN * 2);  // 213 KB
    unsigned short* qb   = (unsigned short*)alloc((size_t)NN * 128 * 2);   // 12.8 MB
    unsigned short* kb   = (unsigned short*)alloc((size_t)NN * 128 * 2);
    unsigned short* vb   = (unsigned short*)alloc((size_t)NN * 128 * 2);
    float*          skip = (float*)alloc((size_t)NN * HDIM * 4);           // 6.4 MB
    int*            deg  = (int*)alloc((size_t)NN * 4);
    int*            cur  = (int*)alloc((size_t)NN * 4);
    int*            rowp = (int*)alloc((size_t)(NN + 1) * 4);
    int*            csrc = (int*)alloc((size_t)EE * 4);                    // 3.2 MB

    hipMemsetAsync(deg, 0, (size_t)NN * 4, stream);
    hipMemsetAsync(cur, 0, (size_t)NN * 4, stream);

    prep_x<<<(NN * CIN / 8 + 255) / 256, 256, 0, stream>>>(x, xb);
    prep_w<<<(416 * 256 + 255) / 256, 256, 0, stream>>>(Wq, Wk, Wv, Ws, WT);

    hist_dst<<<(EE + 255) / 256, 256, 0, stream>>>(ei, deg);
    scan_deg<<<1, 1024, 0, stream>>>(deg, rowp);
    fill_csr<<<(EE + 255) / 256, 256, 0, stream>>>(ei, rowp, cur, csrc);

    dim3 gGemm((NN + 127) / 128, 416 / 32);
    mfma_gemm<<<gGemm, 256, 0, stream>>>(xb, WT, bq, bk, bv, bs, qb, kb, vb, skip);

    fused_edge<<<(NN + 3) / 4, 256, 0, stream>>>(qb, kb, vb, csrc, rowp, skip, out);
}

// Round 4
// 324.452 us; speedup vs baseline: 1.3375x; 1.3375x over previous
//
#include <hip/hip_runtime.h>
#include <hip/hip_bf16.h>

#define NN 50000
#define EE 800000
#define CIN 256
#define HEADS 4
#define HDIM 32
#define SCAN_NB 196   // ceil(NN/256)

typedef float f32x4 __attribute__((ext_vector_type(4)));
typedef __bf16 bf16x8 __attribute__((ext_vector_type(8)));

typedef const __attribute__((address_space(1))) unsigned int* gptr_t;
typedef __attribute__((address_space(3))) unsigned int* lptr_t;

static __device__ __forceinline__ unsigned short f2b(float f) {
    __hip_bfloat16 h = __float2bfloat16(f);
    return *(unsigned short*)&h;
}
static __device__ __forceinline__ float blo(unsigned int u) {
    union { unsigned int i; float f; } c; c.i = u << 16; return c.f;
}
static __device__ __forceinline__ float bhi(unsigned int u) {
    union { unsigned int i; float f; } c; c.i = u & 0xffff0000u; return c.f;
}

// ---------------- prep: x -> bf16 ----------------
__global__ __launch_bounds__(256) void prep_x(const float* __restrict__ x,
                                              unsigned short* __restrict__ xb) {
    const int t = blockIdx.x * 256 + threadIdx.x;
    if (t >= NN * CIN / 8) return;
    const float4 a = ((const float4*)x)[t * 2];
    const float4 b = ((const float4*)x)[t * 2 + 1];
    union { unsigned short us[8]; uint4 v; } o;
    o.us[0] = f2b(a.x); o.us[1] = f2b(a.y); o.us[2] = f2b(a.z); o.us[3] = f2b(a.w);
    o.us[4] = f2b(b.x); o.us[5] = f2b(b.y); o.us[6] = f2b(b.z); o.us[7] = f2b(b.w);
    ((uint4*)xb)[t] = o.v;
}

// ---------------- prep: WT[416][256] bf16 (transposed concat) ----------------
__global__ __launch_bounds__(256) void prep_w(
    const float* __restrict__ Wq, const float* __restrict__ Wk,
    const float* __restrict__ Wv, const float* __restrict__ Ws,
    unsigned short* __restrict__ WT) {
    const int t = blockIdx.x * 256 + threadIdx.x;
    if (t >= 416 * 256) return;
    const int c = t >> 8;
    const int k = t & 255;
    float w;
    if (c < 128)      w = Wq[k * 128 + c];
    else if (c < 256) w = Wk[k * 128 + (c - 128)];
    else if (c < 384) w = Wv[k * 128 + (c - 256)];
    else              w = Ws[k * 32 + (c - 384)];
    WT[t] = f2b(w);
}

// ---------------- MFMA GEMM ----------------
__global__ __launch_bounds__(256) void mfma_gemm(
    const unsigned short* __restrict__ xb, const unsigned short* __restrict__ WT,
    const float* __restrict__ bq, const float* __restrict__ bk,
    const float* __restrict__ bv, const float* __restrict__ bs,
    unsigned short* __restrict__ qb, unsigned short* __restrict__ kb,
    unsigned short* __restrict__ vb, float* __restrict__ skip) {
    __shared__ __hip_bfloat16 As[128 * 32];
    __shared__ __hip_bfloat16 Bs[32 * 32];

    const int row0 = blockIdx.x * 128;
    const int col0 = blockIdx.y * 32;
    const int wave = threadIdx.x >> 6;
    const int lane = threadIdx.x & 63;
    const int lr = lane & 15;
    const int lq = lane >> 4;

    f32x4 acc[2][2] = {};

    for (int k0 = 0; k0 < CIN; k0 += 32) {
        #pragma unroll
        for (int i = 0; i < 2; ++i) {
            const int u = wave * 128 + i * 64 + lane;
            const int r = u >> 2, cb = u & 3;
            int grow = row0 + r; if (grow >= NN) grow = NN - 1;
            __builtin_amdgcn_global_load_lds(
                (gptr_t)(const void*)(xb + (size_t)grow * CIN + k0 + cb * 8),
                (lptr_t)(void*)((__hip_bfloat16*)As + u * 8), 16, 0, 0);
        }
        if (wave < 2) {
            const int u = wave * 64 + lane;
            const int c = u >> 2, cb = u & 3;
            __builtin_amdgcn_global_load_lds(
                (gptr_t)(const void*)(WT + (size_t)(col0 + c) * CIN + k0 + cb * 8),
                (lptr_t)(void*)((__hip_bfloat16*)Bs + u * 8), 16, 0, 0);
        }
        __syncthreads();

        bf16x8 af[2], bfr[2];
        af[0]  = *(const bf16x8*)(As + (wave * 32 +  0 + lr) * 32 + lq * 8);
        af[1]  = *(const bf16x8*)(As + (wave * 32 + 16 + lr) * 32 + lq * 8);
        bfr[0] = *(const bf16x8*)(Bs + ( 0 + lr) * 32 + lq * 8);
        bfr[1] = *(const bf16x8*)(Bs + (16 + lr) * 32 + lq * 8);

        acc[0][0] = __builtin_amdgcn_mfma_f32_16x16x32_bf16(af[0], bfr[0], acc[0][0], 0, 0, 0);
        acc[0][1] = __builtin_amdgcn_mfma_f32_16x16x32_bf16(af[0], bfr[1], acc[0][1], 0, 0, 0);
        acc[1][0] = __builtin_amdgcn_mfma_f32_16x16x32_bf16(af[1], bfr[0], acc[1][0], 0, 0, 0);
        acc[1][1] = __builtin_amdgcn_mfma_f32_16x16x32_bf16(af[1], bfr[1], acc[1][1], 0, 0, 0);
        __syncthreads();
    }

    #pragma unroll
    for (int i = 0; i < 2; ++i)
        #pragma unroll
        for (int j = 0; j < 2; ++j)
            #pragma unroll
            for (int r = 0; r < 4; ++r) {
                const int grow = row0 + wave * 32 + i * 16 + lq * 4 + r;
                if (grow >= NN) continue;
                const int gcol = col0 + j * 16 + lr;
                const float val = acc[i][j][r];
                if (gcol < 128)
                    qb[(size_t)grow * 128 + gcol] = f2b(val + bq[gcol]);
                else if (gcol < 256)
                    kb[(size_t)grow * 128 + gcol - 128] = f2b(val + bk[gcol - 128]);
                else if (gcol < 384)
                    vb[(size_t)grow * 128 + gcol - 256] = f2b(val + bv[gcol - 256]);
                else
                    skip[(size_t)grow * 32 + gcol - 384] = val + bs[gcol - 384];
            }
}

// ---------------- CSR build ----------------
__global__ __launch_bounds__(256) void hist_dst(const int* __restrict__ ei,
                                                int* __restrict__ deg) {
    const int t = blockIdx.x * 256 + threadIdx.x;
    if (t >= EE) return;
    atomicAdd(&deg[ei[EE + t]], 1);
}

// phase 1: per-block (256 elems) sums
__global__ __launch_bounds__(256) void scan_partial(const int* __restrict__ deg,
                                                    int* __restrict__ bsum) {
    __shared__ int red[256];
    const int t = threadIdx.x;
    const int idx = blockIdx.x * 256 + t;
    red[t] = (idx < NN) ? deg[idx] : 0;
    __syncthreads();
    for (int o = 128; o > 0; o >>= 1) {
        if (t < o) red[t] += red[t + o];
        __syncthreads();
    }
    if (t == 0) bsum[blockIdx.x] = red[0];
}

// phase 2: single block scans the 196 partials -> exclusive block offsets
__global__ __launch_bounds__(256) void scan_offsets(const int* __restrict__ bsum,
                                                    int* __restrict__ boff) {
    __shared__ int lds[256];
    const int t = threadIdx.x;
    const int v = (t < SCAN_NB) ? bsum[t] : 0;
    lds[t] = v;
    __syncthreads();
    for (int o = 1; o < 256; o <<= 1) {
        const int u = (t >= o) ? lds[t - o] : 0;
        __syncthreads();
        lds[t] += u;
        __syncthreads();
    }
    if (t < SCAN_NB) boff[t] = lds[t] - v;   // exclusive
}

// phase 3: local exclusive scan + block offset -> row_ptr (incl row_ptr[NN])
__global__ __launch_bounds__(256) void scan_final(const int* __restrict__ deg,
                                                  const int* __restrict__ boff,
                                                  int* __restrict__ row_ptr) {
    __shared__ int lds[256];
    const int t = threadIdx.x;
    const int idx = blockIdx.x * 256 + t;
    const int v = (idx < NN) ? deg[idx] : 0;
    lds[t] = v;
    __syncthreads();
    for (int o = 1; o < 256; o <<= 1) {
        const int u = (t >= o) ? lds[t - o] : 0;
        __syncthreads();
        lds[t] += u;
        __syncthreads();
    }
    if (idx <= NN) row_ptr[idx] = boff[blockIdx.x] + lds[t] - v;
}

__global__ __launch_bounds__(256) void fill_csr(const int* __restrict__ ei,
                                                int* __restrict__ cursor,
                                                int* __restrict__ csr_src) {
    const int t = blockIdx.x * 256 + threadIdx.x;
    if (t >= EE) return;
    const int dst = ei[EE + t];
    const int pos = atomicAdd(&cursor[dst], 1);
    csr_src[pos] = ei[t];
}

// ---------------- fused edge pass: one wave per dst, 4 edges/iteration -----
// lane = e4*16 + h*4 + i : edge-slot e4, head h, dim-chunk i (8 dims)
__global__ __launch_bounds__(256) void fused_edge(
    const unsigned short* __restrict__ qb, const unsigned short* __restrict__ kb,
    const unsigned short* __restrict__ vb, const int* __restrict__ csr_src,
    const int* __restrict__ row_ptr, const float* __restrict__ skip,
    float* __restrict__ out) {
    const int wid = blockIdx.x * 4 + (threadIdx.x >> 6);
    if (wid >= NN) return;
    const int lane = threadIdx.x & 63;
    const int sub = lane & 15;          // h*4 + i -> byte offset sub*16 in row
    const int e4 = lane >> 4;

    const uint4 qu = *(const uint4*)(qb + (size_t)wid * 128 + sub * 8);
    float qf[8];
    qf[0] = blo(qu.x); qf[1] = bhi(qu.x); qf[2] = blo(qu.y); qf[3] = bhi(qu.y);
    qf[4] = blo(qu.z); qf[5] = bhi(qu.z); qf[6] = blo(qu.w); qf[7] = bhi(qu.w);

    const int beg = row_ptr[wid];
    const int end = row_ptr[wid + 1];

    float s = 0.f;
    float acc[8] = {0.f, 0.f, 0.f, 0.f, 0.f, 0.f, 0.f, 0.f};

    for (int p0 = beg; p0 < end; p0 += 4) {
        const int pe = p0 + e4;
        const bool valid = pe < end;
        const int src = csr_src[valid ? pe : beg];
        const uint4 ku = *(const uint4*)(kb + (size_t)src * 128 + sub * 8);
        const uint4 vu = *(const uint4*)(vb + (size_t)src * 128 + sub * 8);

        float d = qf[0] * blo(ku.x) + qf[1] * bhi(ku.x)
                + qf[2] * blo(ku.y) + qf[3] * bhi(ku.y)
                + qf[4] * blo(ku.z) + qf[5] * bhi(ku.z)
                + qf[6] * blo(ku.w) + qf[7] * bhi(ku.w);
        d += __shfl_xor(d, 1);
        d += __shfl_xor(d, 2);
        const float w = valid ? __expf(d * 0.17677669529663687f) : 0.f;
        s += w;
        acc[0] += w * blo(vu.x); acc[1] += w * bhi(vu.x);
        acc[2] += w * blo(vu.y); acc[3] += w * bhi(vu.y);
        acc[4] += w * blo(vu.z); acc[5] += w * bhi(vu.z);
        acc[6] += w * blo(vu.w); acc[7] += w * bhi(vu.w);
    }

    // sum over the 4 edge-slots (lanes xor 16, 32)
    s += __shfl_xor(s, 16); s += __shfl_xor(s, 32);
    #pragma unroll
    for (int j = 0; j < 8; ++j) {
        acc[j] += __shfl_xor(acc[j], 16);
        acc[j] += __shfl_xor(acc[j], 32);
    }
    // per-head normalize (x 0.25 for head mean)
    const float inv = (s > 0.f) ? 0.25f / s : 0.f;
    #pragma unroll
    for (int j = 0; j < 8; ++j) acc[j] *= inv;
    // sum over heads (lanes xor 4, 8)
    #pragma unroll
    for (int j = 0; j < 8; ++j) {
        acc[j] += __shfl_xor(acc[j], 4);
        acc[j] += __shfl_xor(acc[j], 8);
    }

    if (lane < 4) {   // e4==0, h==0, i==lane -> dims lane*8 .. lane*8+7
        const float4 sk0 = *(const float4*)(skip + (size_t)wid * 32 + lane * 8);
        const float4 sk1 = *(const float4*)(skip + (size_t)wid * 32 + lane * 8 + 4);
        float o[8];
        o[0] = acc[0] + sk0.x; o[1] = acc[1] + sk0.y;
        o[2] = acc[2] + sk0.z; o[3] = acc[3] + sk0.w;
        o[4] = acc[4] + sk1.x; o[5] = acc[5] + sk1.y;
        o[6] = acc[6] + sk1.z; o[7] = acc[7] + sk1.w;
        #pragma unroll
        for (int j = 0; j < 8; ++j) o[j] = o[j] > 0.f ? o[j] : 0.1f * o[j];
        *(float4*)(out + (size_t)wid * 32 + lane * 8)     = make_float4(o[0], o[1], o[2], o[3]);
        *(float4*)(out + (size_t)wid * 32 + lane * 8 + 4) = make_float4(o[4], o[5], o[6], o[7]);
    }
}

extern "C" void kernel_launch(void* const* d_in, const int* in_sizes, int n_in,
                              void* d_out, int out_size, void* d_ws, size_t ws_size,
                              hipStream_t stream) {
    const float* x  = (const float*)d_in[0];
    const int*   ei = (const int*)d_in[1];
    const float* Wq = (const float*)d_in[2];
    const float* bq = (const float*)d_in[3];
    const float* Wk = (const float*)d_in[4];
    const float* bk = (const float*)d_in[5];
    const float* Wv = (const float*)d_in[6];
    const float* bv = (const float*)d_in[7];
    const float* Ws = (const float*)d_in[8];
    const float* bs = (const float*)d_in[9];
    float* out = (float*)d_out;

    char* ws = (char*)d_ws;
    size_t off = 0;
    auto alloc = [&](size_t bytes) { void* p = ws + off; off = (off + bytes + 255) & ~(size_t)255; return p; };
    unsigned short* xb   = (unsigned short*)alloc((size_t)NN * CIN * 2);
    unsigned short* WT   = (unsigned short*)alloc((size_t)416 * CIN * 2);
    unsigned short* qb   = (unsigned short*)alloc((size_t)NN * 128 * 2);
    unsigned short* kb   = (unsigned short*)alloc((size_t)NN * 128 * 2);
    unsigned short* vb   = (unsigned short*)alloc((size_t)NN * 128 * 2);
    float*          skip = (float*)alloc((size_t)NN * HDIM * 4);
    int*            deg  = (int*)alloc((size_t)NN * 4);
    int*            cur  = (int*)alloc((size_t)(NN + 1) * 4);
    int*            rowp = (int*)alloc((size_t)(NN + 1) * 4);
    int*            bsum = (int*)alloc((size_t)SCAN_NB * 4);
    int*            boff = (int*)alloc((size_t)SCAN_NB * 4);
    int*            csrc = (int*)alloc((size_t)EE * 4);

    hipMemsetAsync(deg, 0, (size_t)NN * 4, stream);

    prep_x<<<(NN * CIN / 8 + 255) / 256, 256, 0, stream>>>(x, xb);
    prep_w<<<(416 * 256 + 255) / 256, 256, 0, stream>>>(Wq, Wk, Wv, Ws, WT);

    hist_dst<<<(EE + 255) / 256, 256, 0, stream>>>(ei, deg);
    scan_partial<<<SCAN_NB, 256, 0, stream>>>(deg, bsum);
    scan_offsets<<<1, 256, 0, stream>>>(bsum, boff);
    scan_final<<<SCAN_NB, 256, 0, stream>>>(deg, boff, rowp);
    hipMemcpyAsync(cur, rowp, (size_t)NN * 4, hipMemcpyDeviceToDevice, stream);
    fill_csr<<<(EE + 255) / 256, 256, 0, stream>>>(ei, cur, csrc);

    dim3 gGemm((NN + 127) / 128, 416 / 32);
    mfma_gemm<<<gGemm, 256, 0, stream>>>(xb, WT, bq, bk, bv, bs, qb, kb, vb, skip);

    fused_edge<<<(NN + 3) / 4, 256, 0, stream>>>(qb, kb, vb, csrc, rowp, skip, out);
}